// Round 13
// baseline (199.238 us; speedup 1.0000x reference)
//
#include <hip/hip_runtime.h>
#include <hip/hip_bf16.h>
#include <math.h>

// Problem constants
#define D_MODEL 512
#define D_STATE 16
#define DT_RANK 32
#define D_INNER 512
#define BB 4
#define LL 2048
#define MROWS (BB * LL)   // 8192
#define LN_EPS 1e-5f
#define CHUNK 32
#define NCH (LL / CHUNK)  // 64
#define LOG2E 1.44269504f
#define LN2 0.69314718f

typedef __bf16 bf16x8 __attribute__((ext_vector_type(8)));
typedef float f32x4 __attribute__((ext_vector_type(4)));

// ---- bf16 split helpers (RNE) ----
__device__ __forceinline__ ushort f2bf(float x) {
  uint u = __float_as_uint(x);
  u = (u + 0x7fffu + ((u >> 16) & 1u)) >> 16;
  return (ushort)u;
}
__device__ __forceinline__ float bf2f(ushort h) {
  return __uint_as_float(((uint)h) << 16);
}
__device__ __forceinline__ void split2(float x, ushort& hi, ushort& lo) {
  hi = f2bf(x);
  lo = f2bf(x - bf2f(hi));
}

__device__ __forceinline__ void gload_lds16(const void* g, void* l) {
  __builtin_amdgcn_global_load_lds(
      (const __attribute__((address_space(1))) uint32_t*)g,
      (__attribute__((address_space(3))) uint32_t*)l, 16, 0, 0);
}

// ================= split-bf16 MFMA GEMM — 128x128 tile, 64x64 waves ===========
// BK=32, double-buffered LDS (A and B) + issue-early prefetch, LDS XOR swizzle,
// XCD-chunked block swizzle. 48 MFMA : 16 ds_read per wave-K-step (3:1 vs r8 2:1).
// A,B bf16 hi/lo row-major [rows][K].
// EPI 0: C=acc.
// EPI 1: gate-dot: sdot[row] += sum_col relu(acc + e0[batch*512+col])*g2[col].
// EPI 2: C = softplus(acc + e0[col]) via native exp2/log2.
template <int EPI>
__global__ __launch_bounds__(256) void gemm_mfma(const ushort* __restrict__ Ahi,
                                                 const ushort* __restrict__ Alo,
                                                 const ushort* __restrict__ Bhi,
                                                 const ushort* __restrict__ Blo,
                                                 float* __restrict__ C, int ldc, int K,
                                                 int nx, const float* __restrict__ e0,
                                                 const float* __restrict__ g2,
                                                 float* __restrict__ sdot) {
  __shared__ ushort sA[2][2][128][32];  // 32 KiB
  __shared__ ushort sB[2][2][128][32];  // 32 KiB

  const int tid = threadIdx.x;
  const int lane = tid & 63;
  const int wid = tid >> 6;  // 0..3

  // XCD-chunked bijective swizzle (nwg % 8 == 0 for all our grids)
  const int nwg = gridDim.x;
  const int q = nwg >> 3;
  const int t = (blockIdx.x & 7) * q + (blockIdx.x >> 3);
  const int bx = t % nx;
  const int by = t / nx;
  const int m0 = by * 128;
  const int n0 = bx * 128;

  // ---- staging addressing (pre-swizzled global source, linear LDS dest) ----
  const int srow = tid >> 2;                                  // 0..63
  const int koff = (((tid & 3) ^ ((tid >> 3) & 3)) << 3);     // swizzled k slot
  const ushort* Ah_p = Ahi + (size_t)(m0 + srow) * K + koff;
  const ushort* Al_p = Alo + (size_t)(m0 + srow) * K + koff;
  const ushort* Bh_p = Bhi + (size_t)(n0 + srow) * K + koff;
  const ushort* Bl_p = Blo + (size_t)(n0 + srow) * K + koff;
  const size_t rstep = (size_t)64 * K;
  const int wb = wid * 16;  // wave-uniform LDS row base

  // ---- compute addressing: 2x2 waves, each 64x64 ----
  const int wr = wid >> 1, wc = wid & 1;
  const int fr = lane & 15;
  const int rcs = (((lane >> 4) ^ ((fr >> 1) & 3)) << 3);  // swizzled read slot

  f32x4 acc[4][4] = {};

  auto STAGE = [&](int bq, int kk) {
    gload_lds16(Ah_p + kk,         &sA[bq][0][wb][0]);
    gload_lds16(Ah_p + kk + rstep, &sA[bq][0][64 + wb][0]);
    gload_lds16(Al_p + kk,         &sA[bq][1][wb][0]);
    gload_lds16(Al_p + kk + rstep, &sA[bq][1][64 + wb][0]);
    gload_lds16(Bh_p + kk,         &sB[bq][0][wb][0]);
    gload_lds16(Bh_p + kk + rstep, &sB[bq][0][64 + wb][0]);
    gload_lds16(Bl_p + kk,         &sB[bq][1][wb][0]);
    gload_lds16(Bl_p + kk + rstep, &sB[bq][1][64 + wb][0]);
  };

  int cur = 0;
  STAGE(0, 0);
  __syncthreads();

  for (int k0 = 0; k0 < K; k0 += 32) {
    if (k0 + 32 < K) STAGE(cur ^ 1, k0 + 32);  // prefetch in flight under MFMA
    bf16x8 ah[4], al[4], bh[4], bl[4];
#pragma unroll
    for (int m = 0; m < 4; ++m) {
      const int ar = wr * 64 + m * 16 + fr;
      ah[m] = *(const bf16x8*)&sA[cur][0][ar][rcs];
      al[m] = *(const bf16x8*)&sA[cur][1][ar][rcs];
    }
#pragma unroll
    for (int n = 0; n < 4; ++n) {
      const int br = wc * 64 + n * 16 + fr;
      bh[n] = *(const bf16x8*)&sB[cur][0][br][rcs];
      bl[n] = *(const bf16x8*)&sB[cur][1][br][rcs];
    }
#pragma unroll
    for (int m = 0; m < 4; ++m)
#pragma unroll
      for (int n = 0; n < 4; ++n) {
        acc[m][n] = __builtin_amdgcn_mfma_f32_16x16x32_bf16(ah[m], bh[n],
                                                            acc[m][n], 0, 0, 0);
        acc[m][n] = __builtin_amdgcn_mfma_f32_16x16x32_bf16(ah[m], bl[n],
                                                            acc[m][n], 0, 0, 0);
        acc[m][n] = __builtin_amdgcn_mfma_f32_16x16x32_bf16(al[m], bh[n],
                                                            acc[m][n], 0, 0, 0);
      }
    __syncthreads();
    cur ^= 1;
  }

  // epilogue: C/D layout col = lane&15, row = (lane>>4)*4 + r
  const int rbase = (lane >> 4) * 4;
  if (EPI == 1) {
    // gate-dot: lane owns 4 cols; 16-lane group shares row for fixed (m,r).
    float g2v[4];
#pragma unroll
    for (int n = 0; n < 4; ++n) g2v[n] = g2[n0 + wc * 64 + n * 16 + fr];
#pragma unroll
    for (int m = 0; m < 4; ++m) {
#pragma unroll
      for (int r = 0; r < 4; ++r) {
        const int row = m0 + wr * 64 + m * 16 + rbase + r;
        const int bofs = (row >> 11) * D_MODEL;
        float val = 0.f;
#pragma unroll
        for (int n = 0; n < 4; ++n) {
          const int col = n0 + wc * 64 + n * 16 + fr;
          val = fmaf(fmaxf(acc[m][n][r] + e0[bofs + col], 0.f), g2v[n], val);
        }
        val += __shfl_xor(val, 1);
        val += __shfl_xor(val, 2);
        val += __shfl_xor(val, 4);
        val += __shfl_xor(val, 8);
        if (fr == 0) atomicAdd(&sdot[row], val);
      }
    }
  } else {
#pragma unroll
    for (int m = 0; m < 4; ++m) {
      const int row0 = m0 + wr * 64 + m * 16 + rbase;
#pragma unroll
      for (int n = 0; n < 4; ++n) {
        const int col = n0 + wc * 64 + n * 16 + fr;
#pragma unroll
        for (int r = 0; r < 4; ++r) {
          float v = acc[m][n][r];
          const int row = row0 + r;
          if (EPI == 2) {
            const float x = v + e0[col];
            const float e = __builtin_amdgcn_exp2f(-fabsf(x) * LOG2E);
            v = fmaxf(x, 0.f) + __log2f(1.f + e) * LN2;
          }
          C[(size_t)row * ldc + col] = v;
        }
      }
    }
  }
}

// ================= BC GEMM (r8-proven): BC(M,32) = A(M,512) @ Wbc(32,512)^T ====
__global__ __launch_bounds__(256) void bc_gemm(const ushort* __restrict__ Ahi,
                                               const ushort* __restrict__ Alo,
                                               const ushort* __restrict__ Bhi,
                                               const ushort* __restrict__ Blo,
                                               float* __restrict__ BC) {
  __shared__ ushort sA[2][2][64][32];  // 16 KiB
  __shared__ ushort sB[2][2][32][32];  // 8 KiB
  const int K = 512;
  const int tid = threadIdx.x;
  const int lane = tid & 63;
  const int wid = tid >> 6;
  const int m0 = blockIdx.x * 64;

  const int srow = lane >> 2;  // 0..15
  const int koff = (((lane & 3) ^ ((lane >> 3) & 3)) << 3);
  const ushort* Ah_p = Ahi + (size_t)(m0 + wid * 16 + srow) * K + koff;
  const ushort* Al_p = Alo + (size_t)(m0 + wid * 16 + srow) * K + koff;
  const ushort* B_p = ((wid < 2) ? Bhi : Blo) + (size_t)((wid & 1) * 16 + srow) * K + koff;

  const int wr = wid >> 1, wc = wid & 1;
  const int fr = lane & 15;
  const int rcs = (((lane >> 4) ^ ((fr >> 1) & 3)) << 3);

  f32x4 acc[2] = {};

  auto STAGE = [&](int bq, int kk) {
    gload_lds16(Ah_p + kk, &sA[bq][0][wid * 16][0]);
    gload_lds16(Al_p + kk, &sA[bq][1][wid * 16][0]);
    gload_lds16(B_p + kk, &sB[bq][wid >> 1][(wid & 1) * 16][0]);
  };

  int cur = 0;
  STAGE(0, 0);
  __syncthreads();

  for (int k0 = 0; k0 < K; k0 += 32) {
    if (k0 + 32 < K) STAGE(cur ^ 1, k0 + 32);
    bf16x8 ah[2], al[2], bh, bl;
#pragma unroll
    for (int m = 0; m < 2; ++m) {
      const int ar = wr * 32 + m * 16 + fr;
      ah[m] = *(const bf16x8*)&sA[cur][0][ar][rcs];
      al[m] = *(const bf16x8*)&sA[cur][1][ar][rcs];
    }
    const int br = wc * 16 + fr;
    bh = *(const bf16x8*)&sB[cur][0][br][rcs];
    bl = *(const bf16x8*)&sB[cur][1][br][rcs];
#pragma unroll
    for (int m = 0; m < 2; ++m) {
      acc[m] = __builtin_amdgcn_mfma_f32_16x16x32_bf16(ah[m], bh, acc[m], 0, 0, 0);
      acc[m] = __builtin_amdgcn_mfma_f32_16x16x32_bf16(ah[m], bl, acc[m], 0, 0, 0);
      acc[m] = __builtin_amdgcn_mfma_f32_16x16x32_bf16(al[m], bh, acc[m], 0, 0, 0);
    }
    __syncthreads();
    cur ^= 1;
  }

  const int rbase = (lane >> 4) * 4;
  const int col = wc * 16 + fr;
#pragma unroll
  for (int m = 0; m < 2; ++m) {
    const int row0 = m0 + wr * 32 + m * 16 + rbase;
#pragma unroll
    for (int r = 0; r < 4; ++r)
      BC[(size_t)(row0 + r) * 32 + col] = acc[m][r];
  }
}

// ---------------- prep: split_x + weight prep + c1 in ONE dispatch -------------
__global__ __launch_bounds__(256) void prep_all(const float* __restrict__ x,
                                                const float* __restrict__ gW1,
                                                const float* __restrict__ ipW,
                                                const float* __restrict__ opW,
                                                const float* __restrict__ xW,
                                                const float* __restrict__ dtW,
                                                const float* __restrict__ xstats,
                                                const float* __restrict__ gb1,
                                                ushort* __restrict__ XShi,
                                                ushort* __restrict__ XSlo,
                                                ushort* __restrict__ Whi,
                                                ushort* __restrict__ Wlo,
                                                float* __restrict__ c1) {
  const int blk = blockIdx.x;
  const int tid = threadIdx.x;
  if (blk < 4096) {
    const int i = (blk * 256 + tid) * 4;
    float4 v = *(const float4*)(x + i);
    ushort h0, l0, h1, l1, h2, l2, h3, l3;
    split2(v.x, h0, l0); split2(v.y, h1, l1);
    split2(v.z, h2, l2); split2(v.w, h3, l3);
    ushort4 hv = {h0, h1, h2, h3}, lv = {l0, l1, l2, l3};
    *(ushort4*)(XShi + i) = hv;
    *(ushort4*)(XSlo + i) = lv;
    return;
  }
  if (blk < 4096 + 1296) {
    const int sub = tid >> 7;
    const int tt = tid & 127;
    const int r = (blk - 4096) * 2 + sub;
    const int j = r - 2048;
    __shared__ float sdt[2][32];
    if (tt < 32 && j >= 0 && j < 512) sdt[sub][tt] = dtW[j * 32 + tt];
    __syncthreads();
    float v[4] = {0.f, 0.f, 0.f, 0.f};
    if (r < 2048) {
      const float* src = (r < 512)    ? gW1 + (size_t)r * 1024
                         : (r < 1536) ? ipW + (size_t)(r - 512) * 512
                                      : opW + (size_t)(r - 1536) * 512;
      const float4 xv = *(const float4*)(src + tt * 4);
      v[0] = xv.x; v[1] = xv.y; v[2] = xv.z; v[3] = xv.w;
    } else if (j < 512) {  // W_comb row
      const int k = tt * 4;
#pragma unroll 8
      for (int rr = 0; rr < 32; ++rr) {
        const float w = sdt[sub][rr];
        const float4 xv = *(const float4*)(xW + rr * 512 + k);
        v[0] = fmaf(w, xv.x, v[0]);
        v[1] = fmaf(w, xv.y, v[1]);
        v[2] = fmaf(w, xv.z, v[2]);
        v[3] = fmaf(w, xv.w, v[3]);
      }
    } else {  // B,C rows
      const float4 xv = *(const float4*)(xW + (size_t)(32 + j - 512) * 512 + tt * 4);
      v[0] = xv.x; v[1] = xv.y; v[2] = xv.z; v[3] = xv.w;
    }
    ushort h[4], l[4];
#pragma unroll
    for (int c = 0; c < 4; ++c) split2(v[c], h[c], l[c]);
    const size_t off = (size_t)r * 512 + tt * 4;
    ushort4 hv = {h[0], h[1], h[2], h[3]}, lv = {l[0], l[1], l[2], l[3]};
    *(ushort4*)(Whi + off) = hv;
    *(ushort4*)(Wlo + off) = lv;
    return;
  }
  // c1
  const int c = blk - (4096 + 1296);
  const int b = c >> 1;
  const int j = ((c & 1) << 8) + tid;
  float acc = gb1[j];
  const float* xs = xstats + b * D_MODEL;
  const float* w = gW1 + (size_t)j * (2 * D_MODEL) + D_MODEL;
  for (int k = 0; k < D_MODEL; k += 4) {
    acc = fmaf(xs[k], w[k], acc);
    acc = fmaf(xs[k + 1], w[k + 1], acc);
    acc = fmaf(xs[k + 2], w[k + 2], acc);
    acc = fmaf(xs[k + 3], w[k + 3], acc);
  }
  c1[b * D_MODEL + j] = acc;
}

// ---------------- block reduce ------------------------------------------------
__device__ __forceinline__ float block_sum(float v, float* sm) {
#pragma unroll
  for (int m = 32; m; m >>= 1) v += __shfl_xor(v, m);
  const int lane = threadIdx.x & 63, w = threadIdx.x >> 6;
  __syncthreads();
  if (!lane) sm[w] = v;
  __syncthreads();
  return sm[0] + sm[1] + sm[2] + sm[3];
}

// ---------------- gate + layernorm (reads precomputed gate dot) ----------------
__global__ __launch_bounds__(256) void gate_ln_kernel(const float* __restrict__ sdot,
                                                      const float* __restrict__ xsig,
                                                      const float* __restrict__ xstats,
                                                      const float* __restrict__ gb2,
                                                      const float* __restrict__ ln_g,
                                                      const float* __restrict__ ln_b,
                                                      ushort* __restrict__ XNhi,
                                                      ushort* __restrict__ XNlo) {
  __shared__ float red[4];
  const int row = blockIdx.x;
  const int b = row >> 11;
  const int tid = threadIdx.x;
  const size_t rb = (size_t)row * D_MODEL;

  const float gate = 1.f / (1.f + expf(-(sdot[row] + gb2[0])));

  float xr[2];
#pragma unroll
  for (int ii = 0; ii < 2; ++ii) {
    const int j = tid + ii * 256;
    xr[ii] = xsig[rb + j] + gate * xstats[b * D_MODEL + j];
  }
  float sv = xr[0] + xr[1];
  const float mu = block_sum(sv, red) * (1.f / D_MODEL);
  float s2 = (xr[0] - mu) * (xr[0] - mu) + (xr[1] - mu) * (xr[1] - mu);
  const float var = block_sum(s2, red) * (1.f / D_MODEL);
  const float inv = rsqrtf(var + LN_EPS);
#pragma unroll
  for (int ii = 0; ii < 2; ++ii) {
    const int j = tid + ii * 256;
    const float v = (xr[ii] - mu) * inv * ln_g[j] + ln_b[j];
    ushort h, l;
    split2(v, h, l);
    XNhi[rb + j] = h;
    XNlo[rb + j] = l;
  }
}

// ---------------- causal conv(2) + SiLU — row-block, single-pass reads ---------
__global__ __launch_bounds__(256) void conv_silu_kernel(const float* __restrict__ XZ,
                                                        const float* __restrict__ conv_w,
                                                        const float* __restrict__ conv_b,
                                                        ushort* __restrict__ Uhi,
                                                        ushort* __restrict__ Ulo) {
  const int base = blockIdx.x * 16;
  const int j = threadIdx.x * 2;
  const float w0a = conv_w[j * 2 + 0], w1a = conv_w[j * 2 + 1];
  const float w0b = conv_w[j * 2 + 2], w1b = conv_w[j * 2 + 3];
  const float ba = conv_b[j], bb = conv_b[j + 1];
  float2 prev;
  if ((base & (LL - 1)) == 0) {
    prev.x = 0.f; prev.y = 0.f;
  } else {
    prev = *(const float2*)(XZ + (size_t)(base - 1) * (2 * D_INNER) + j);
  }
#pragma unroll 4
  for (int t = 0; t < 16; ++t) {
    const size_t r = base + t;
    const float2 cur = *(const float2*)(XZ + r * (2 * D_INNER) + j);
    float va = ba + w0a * prev.x + w1a * cur.x;
    float vb = bb + w0b * prev.y + w1b * cur.y;
    va = va / (1.f + __builtin_amdgcn_exp2f(-va * LOG2E));
    vb = vb / (1.f + __builtin_amdgcn_exp2f(-vb * LOG2E));
    ushort ha, la, hb, lb;
    split2(va, ha, la);
    split2(vb, hb, lb);
    ushort2 hv = {ha, hb}, lv = {la, lb};
    *(ushort2*)(Uhi + r * D_INNER + j) = hv;
    *(ushort2*)(Ulo + r * D_INNER + j) = lv;
    prev = cur;
  }
}

// ---------------- chunked selective scan (CHUNK=32, r8-proven) -----------------
__global__ __launch_bounds__(256) void scan_part1(const float* __restrict__ DELTA,
                                                  const ushort* __restrict__ Uhi,
                                                  const ushort* __restrict__ Ulo,
                                                  const float* __restrict__ BC,
                                                  const float* __restrict__ A_log,
                                                  float* __restrict__ SLOC,
                                                  float* __restrict__ DSUM) {
  __shared__ __align__(16) float sBC[CHUNK][32];
  const int tid = threadIdx.x;
  const int bid = blockIdx.x;
  const int d = ((bid & 1) << 8) + tid;
  const int c = (bid >> 1) & (NCH - 1);
  const int b = bid >> 7;
  const size_t base = (size_t)b * LL + (size_t)c * CHUNK;

  {
    const int row = tid >> 3, col = (tid & 7) << 2;
    *(float4*)&sBC[row][col] = *(const float4*)(BC + (base + row) * 32 + col);
  }
  float A2[16];
#pragma unroll
  for (int n = 0; n < 16; ++n) A2[n] = -expf(A_log[d * 16 + n]) * LOG2E;
  __syncthreads();

  float S[16];
#pragma unroll
  for (int n = 0; n < 16; ++n) S[n] = 0.f;
  float dsum = 0.f;

#pragma unroll 2
  for (int t = 0; t < CHUNK; ++t) {
    const size_t r = base + t;
    const float delta = DELTA[r * D_INNER + d];
    const float u = bf2f(Uhi[r * D_INNER + d]) + bf2f(Ulo[r * D_INNER + d]);
    dsum += delta;
    const float du = delta * u;
    float Bv[16];
#pragma unroll
    for (int i = 0; i < 4; ++i)
      *(float4*)&Bv[i * 4] = *(const float4*)&sBC[t][i * 4];
#pragma unroll
    for (int n = 0; n < 16; ++n) {
      const float dA = __builtin_amdgcn_exp2f(delta * A2[n]);
      S[n] = fmaf(dA, S[n], du * Bv[n]);
    }
  }
  const size_t ci = ((size_t)b * NCH + c) * D_INNER + d;
#pragma unroll
  for (int i = 0; i < 4; ++i)
    *(float4*)(SLOC + ci * 16 + i * 4) = *(const float4*)&S[i * 4];
  DSUM[ci] = dsum;
}

__global__ __launch_bounds__(256) void scan_combine(const float* __restrict__ SLOC,
                                                    const float* __restrict__ DSUM,
                                                    const float* __restrict__ A_log,
                                                    float* __restrict__ HINIT) {
  const int idx = blockIdx.x * 256 + threadIdx.x;  // 0..32767
  const int b = idx >> 13;
  const int d = (idx >> 4) & (D_INNER - 1);
  const int n = idx & 15;
  const float A2 = -expf(A_log[d * D_STATE + n]) * LOG2E;
  float h = 0.f;
#pragma unroll 4
  for (int c = 0; c < NCH; ++c) {
    const size_t ci = ((size_t)b * NCH + c) * D_INNER + d;
    HINIT[ci * 16 + n] = h;
    const float a = __builtin_amdgcn_exp2f(A2 * DSUM[ci]);
    h = fmaf(a, h, SLOC[ci * 16 + n]);
  }
}

__global__ __launch_bounds__(256) void scan_part3(const float* __restrict__ DELTA,
                                                  const ushort* __restrict__ Uhi,
                                                  const ushort* __restrict__ Ulo,
                                                  const float* __restrict__ BC,
                                                  const float* __restrict__ XZ,
                                                  const float* __restrict__ A_log,
                                                  const float* __restrict__ Dp,
                                                  const float* __restrict__ HINIT,
                                                  ushort* __restrict__ Yhi,
                                                  ushort* __restrict__ Ylo) {
  __shared__ __align__(16) float sBC[CHUNK][32];
  const int tid = threadIdx.x;
  const int bid = blockIdx.x;
  const int d = ((bid & 1) << 8) + tid;
  const int c = (bid >> 1) & (NCH - 1);
  const int b = bid >> 7;
  const size_t base = (size_t)b * LL + (size_t)c * CHUNK;

  {
    const int row = tid >> 3, col = (tid & 7) << 2;
    *(float4*)&sBC[row][col] = *(const float4*)(BC + (base + row) * 32 + col);
  }
  float A2[16];
#pragma unroll
  for (int n = 0; n < 16; ++n) A2[n] = -expf(A_log[d * 16 + n]) * LOG2E;
  const float Dpd = Dp[d];

  const size_t ci = ((size_t)b * NCH + c) * D_INNER + d;
  float h[16];
#pragma unroll
  for (int i = 0; i < 4; ++i)
    *(float4*)&h[i * 4] = *(const float4*)(HINIT + ci * 16 + i * 4);
  __syncthreads();

#pragma unroll 2
  for (int t = 0; t < CHUNK; ++t) {
    const size_t r = base + t;
    const float delta = DELTA[r * D_INNER + d];
    const float u = bf2f(Uhi[r * D_INNER + d]) + bf2f(Ulo[r * D_INNER + d]);
    const float z = XZ[r * (2 * D_INNER) + D_INNER + d];
    const float du = delta * u;
    float BCv[32];
#pragma unroll
    for (int i = 0; i < 8; ++i)
      *(float4*)&BCv[i * 4] = *(const float4*)&sBC[t][i * 4];
    float y = 0.f;
#pragma unroll
    for (int n = 0; n < 16; ++n) {
      const float dA = __builtin_amdgcn_exp2f(delta * A2[n]);
      h[n] = fmaf(dA, h[n], du * BCv[n]);
      y = fmaf(h[n], BCv[16 + n], y);
    }
    const float sz = z / (1.f + __builtin_amdgcn_exp2f(-z * LOG2E));
    const float o = (y + Dpd * u) * sz;
    ushort hh, ll;
    split2(o, hh, ll);
    Yhi[r * D_INNER + d] = hh;
    Ylo[r * D_INNER + d] = ll;
  }
}

// =============================================================================
extern "C" void kernel_launch(void* const* d_in, const int* in_sizes, int n_in,
                              void* d_out, int out_size, void* d_ws, size_t ws_size,
                              hipStream_t stream) {
  const float* x_signal = (const float*)d_in[0];
  const float* x_stats  = (const float*)d_in[1];
  const float* gW1      = (const float*)d_in[2];
  const float* gb1      = (const float*)d_in[3];
  const float* gW2      = (const float*)d_in[4];
  const float* gb2      = (const float*)d_in[5];
  const float* ln_g     = (const float*)d_in[6];
  const float* ln_b     = (const float*)d_in[7];
  const float* in_proj_W = (const float*)d_in[8];
  const float* conv_w   = (const float*)d_in[9];
  const float* conv_b   = (const float*)d_in[10];
  const float* x_proj_W = (const float*)d_in[11];
  const float* dt_proj_W = (const float*)d_in[12];
  const float* dt_proj_b = (const float*)d_in[13];
  const float* A_log    = (const float*)d_in[14];
  const float* Dp       = (const float*)d_in[15];
  const float* out_proj_W = (const float*)d_in[16];
  float* out = (float*)d_out;

  float* ws = (float*)d_ws;
  const size_t NE = (size_t)MROWS * D_MODEL;  // 4,194,304
  float* H    = ws;                     // Yhi/Ylo region
  float* XNf  = H + NE;                 // XN hi/lo bf16; later DELTA f32
  float* XZ   = XNf + NE;               // 8192x1024 f32; first XShi/XSlo
  float* UHL  = XZ + 2 * NE;            // Uhi/Ulo bf16
  float* BC   = UHL + NE;               // 8192x32 f32
  float* C1   = BC + (size_t)MROWS * 32;
  float* SGATE = C1 + BB * D_MODEL;     // 8192 f32 gate dots
  float* SLOC = SGATE + MROWS;
  float* DSUM = SLOC + (size_t)BB * NCH * D_INNER * D_STATE;
  float* HINIT = DSUM + (size_t)BB * NCH * D_INNER;
  float* WSP  = HINIT + (size_t)BB * NCH * D_INNER * D_STATE;

  ushort* XNhi = (ushort*)XNf;
  ushort* XNlo = XNhi + NE;
  ushort* XShi = (ushort*)XZ;
  ushort* XSlo = XShi + NE;
  ushort* Yhi  = (ushort*)H;
  ushort* Ylo  = Yhi + NE;
  ushort* Uhi  = (ushort*)UHL;
  ushort* Ulo  = Uhi + NE;
  ushort* Whi  = (ushort*)WSP;          // 2592 rows x 512
  ushort* Wlo  = Whi + (size_t)2592 * 512;
  float* DELTA = XNf;

  // 0) zero gate dots; split x / prep weights / c1 in one dispatch
  hipMemsetAsync(SGATE, 0, MROWS * sizeof(float), stream);
  prep_all<<<dim3(4096 + 1296 + 8), dim3(256), 0, stream>>>(
      x_signal, gW1, in_proj_W, out_proj_W, x_proj_W, dt_proj_W, x_stats, gb1,
      XShi, XSlo, Whi, Wlo, C1);

  // 1) gate dots: SGATE[row] = sum relu(x@W1a + c1)*gW2  (grid 4x64 = 256)
  gemm_mfma<1><<<dim3(4 * 64), dim3(256), 0, stream>>>(
      XShi, XSlo, Whi, Wlo, nullptr, 0, D_MODEL, 4, C1, gW2, SGATE);

  // 2) gate + layernorm -> XNhi/XNlo
  gate_ln_kernel<<<dim3(MROWS), dim3(256), 0, stream>>>(SGATE, x_signal, x_stats,
                                                        gb2, ln_g, ln_b, XNhi, XNlo);

  // 3) XZ = XN @ in_proj_W.T   (grid 8x64 = 512)
  gemm_mfma<0><<<dim3(8 * 64), dim3(256), 0, stream>>>(
      XNhi, XNlo, Whi + (size_t)512 * 512, Wlo + (size_t)512 * 512, XZ, 2 * D_INNER,
      D_MODEL, 8, nullptr, nullptr, nullptr);

  // 4) conv + silu -> Uhi/Ulo  (grid 512, 16 rows/block)
  conv_silu_kernel<<<dim3(MROWS / 16), dim3(256), 0, stream>>>(XZ, conv_w, conv_b,
                                                               Uhi, Ulo);

  // 5a) DELTA = softplus(U @ Wcomb.T + dtb)  (grid 4x64 = 256)
  gemm_mfma<2><<<dim3(4 * 64), dim3(256), 0, stream>>>(
      Uhi, Ulo, Whi + (size_t)2048 * 512, Wlo + (size_t)2048 * 512, DELTA, 512,
      D_MODEL, 4, dt_proj_b, nullptr, nullptr);

  // 5b) BC = U @ xWbc.T  (N=32, grid 128)
  bc_gemm<<<dim3(MROWS / 64), dim3(256), 0, stream>>>(
      Uhi, Ulo, Whi + (size_t)2560 * 512, Wlo + (size_t)2560 * 512, BC);

  // 6) chunked selective scan (CHUNK=32) -> Yhi/Ylo
  scan_part1<<<dim3(BB * NCH * 2), dim3(256), 0, stream>>>(DELTA, Uhi, Ulo, BC, A_log,
                                                           SLOC, DSUM);
  scan_combine<<<dim3(128), dim3(256), 0, stream>>>(SLOC, DSUM, A_log, HINIT);
  scan_part3<<<dim3(BB * NCH * 2), dim3(256), 0, stream>>>(DELTA, Uhi, Ulo, BC, XZ,
                                                           A_log, Dp, HINIT, Yhi, Ylo);

  // 7) out = Y @ out_proj_W.T   (grid 4x64 = 256)
  gemm_mfma<0><<<dim3(4 * 64), dim3(256), 0, stream>>>(
      Yhi, Ylo, Whi + (size_t)1536 * 512, Wlo + (size_t)1536 * 512, out, D_MODEL,
      D_INNER, 4, nullptr, nullptr, nullptr);
}

// Round 14
// 183.587 us; speedup vs baseline: 1.0853x; 1.0853x over previous
//
#include <hip/hip_runtime.h>
#include <hip/hip_bf16.h>
#include <math.h>

// Problem constants
#define D_MODEL 512
#define D_STATE 16
#define DT_RANK 32
#define D_INNER 512
#define BB 4
#define LL 2048
#define MROWS (BB * LL)   // 8192
#define LN_EPS 1e-5f
#define CHUNK 32
#define NCH (LL / CHUNK)  // 64
#define LOG2E 1.44269504f
#define LN2 0.69314718f

typedef __bf16 bf16x8 __attribute__((ext_vector_type(8)));
typedef float f32x4 __attribute__((ext_vector_type(4)));

// ---- bf16 split helpers (RNE) ----
__device__ __forceinline__ ushort f2bf(float x) {
  uint u = __float_as_uint(x);
  u = (u + 0x7fffu + ((u >> 16) & 1u)) >> 16;
  return (ushort)u;
}
__device__ __forceinline__ float bf2f(ushort h) {
  return __uint_as_float(((uint)h) << 16);
}
__device__ __forceinline__ void split2(float x, ushort& hi, ushort& lo) {
  hi = f2bf(x);
  lo = f2bf(x - bf2f(hi));
}

__device__ __forceinline__ void gload_lds16(const void* g, void* l) {
  __builtin_amdgcn_global_load_lds(
      (const __attribute__((address_space(1))) uint32_t*)g,
      (__attribute__((address_space(3))) uint32_t*)l, 16, 0, 0);
}

// ================= split-bf16 MFMA GEMM (r12 structure, 196us-proven) =========
// Tile 128x64, BK=32, double-buffered LDS (A and B) + issue-early prefetch,
// LDS XOR swizzle, XCD-chunked block swizzle. A,B bf16 hi/lo row-major [rows][K].
// EPI 0: C=acc.
// EPI 1: gate-dot: sdot[row] += sum_col relu(acc + e0[batch*512+col])*g2[col].
template <int EPI>
__global__ __launch_bounds__(256) void gemm_mfma(const ushort* __restrict__ Ahi,
                                                 const ushort* __restrict__ Alo,
                                                 const ushort* __restrict__ Bhi,
                                                 const ushort* __restrict__ Blo,
                                                 float* __restrict__ C, int ldc, int K,
                                                 int nx, const float* __restrict__ e0,
                                                 const float* __restrict__ g2,
                                                 float* __restrict__ sdot) {
  __shared__ ushort sA[2][2][128][32];  // 32 KiB
  __shared__ ushort sB[2][2][64][32];   // 16 KiB

  const int tid = threadIdx.x;
  const int lane = tid & 63;
  const int wid = tid >> 6;  // 0..3

  const int nwg = gridDim.x;
  const int q = nwg >> 3;
  const int t = (blockIdx.x & 7) * q + (blockIdx.x >> 3);
  const int bx = t % nx;
  const int by = t / nx;
  const int m0 = by * 128;
  const int n0 = bx * 64;

  const int srow = tid >> 2;
  const int koff = (((tid & 3) ^ ((tid >> 3) & 3)) << 3);
  const ushort* Ah_p = Ahi + (size_t)(m0 + srow) * K + koff;
  const ushort* Al_p = Alo + (size_t)(m0 + srow) * K + koff;
  const ushort* Bh_p = Bhi + (size_t)(n0 + srow) * K + koff;
  const ushort* Bl_p = Blo + (size_t)(n0 + srow) * K + koff;
  const size_t rstep = (size_t)64 * K;
  const int wb = wid * 16;

  const int wr = wid >> 1, wc = wid & 1;
  const int fr = lane & 15;
  const int rcs = (((lane >> 4) ^ ((fr >> 1) & 3)) << 3);

  f32x4 acc[4][2] = {};

  auto STAGE = [&](int bq, int kk) {
    gload_lds16(Ah_p + kk,         &sA[bq][0][wb][0]);
    gload_lds16(Ah_p + kk + rstep, &sA[bq][0][64 + wb][0]);
    gload_lds16(Al_p + kk,         &sA[bq][1][wb][0]);
    gload_lds16(Al_p + kk + rstep, &sA[bq][1][64 + wb][0]);
    gload_lds16(Bh_p + kk,         &sB[bq][0][wb][0]);
    gload_lds16(Bl_p + kk,         &sB[bq][1][wb][0]);
  };

  int cur = 0;
  STAGE(0, 0);
  __syncthreads();

  for (int k0 = 0; k0 < K; k0 += 32) {
    if (k0 + 32 < K) STAGE(cur ^ 1, k0 + 32);
    bf16x8 ah[4], al[4], bh[2], bl[2];
#pragma unroll
    for (int m = 0; m < 4; ++m) {
      const int ar = wr * 64 + m * 16 + fr;
      ah[m] = *(const bf16x8*)&sA[cur][0][ar][rcs];
      al[m] = *(const bf16x8*)&sA[cur][1][ar][rcs];
    }
#pragma unroll
    for (int n = 0; n < 2; ++n) {
      const int br = wc * 32 + n * 16 + fr;
      bh[n] = *(const bf16x8*)&sB[cur][0][br][rcs];
      bl[n] = *(const bf16x8*)&sB[cur][1][br][rcs];
    }
#pragma unroll
    for (int m = 0; m < 4; ++m)
#pragma unroll
      for (int n = 0; n < 2; ++n) {
        acc[m][n] = __builtin_amdgcn_mfma_f32_16x16x32_bf16(ah[m], bh[n],
                                                            acc[m][n], 0, 0, 0);
        acc[m][n] = __builtin_amdgcn_mfma_f32_16x16x32_bf16(ah[m], bl[n],
                                                            acc[m][n], 0, 0, 0);
        acc[m][n] = __builtin_amdgcn_mfma_f32_16x16x32_bf16(al[m], bh[n],
                                                            acc[m][n], 0, 0, 0);
      }
    __syncthreads();
    cur ^= 1;
  }

  const int rbase = (lane >> 4) * 4;
  if (EPI == 1) {
    const int c0 = n0 + wc * 32 + fr;
    const int c1c = n0 + wc * 32 + 16 + fr;
    const float g2a = g2[c0];
    const float g2b = g2[c1c];
#pragma unroll
    for (int m = 0; m < 4; ++m) {
#pragma unroll
      for (int r = 0; r < 4; ++r) {
        const int row = m0 + wr * 64 + m * 16 + rbase + r;
        const int bofs = (row >> 11) * D_MODEL;
        const float v0 = fmaxf(acc[m][0][r] + e0[bofs + c0], 0.f);
        const float v1 = fmaxf(acc[m][1][r] + e0[bofs + c1c], 0.f);
        float val = fmaf(v0, g2a, v1 * g2b);
        val += __shfl_xor(val, 1);
        val += __shfl_xor(val, 2);
        val += __shfl_xor(val, 4);
        val += __shfl_xor(val, 8);
        if (fr == 0) atomicAdd(&sdot[row], val);
      }
    }
  } else {
#pragma unroll
    for (int m = 0; m < 4; ++m) {
      const int row0 = m0 + wr * 64 + m * 16 + rbase;
#pragma unroll
      for (int n = 0; n < 2; ++n) {
        const int col = n0 + wc * 32 + n * 16 + fr;
#pragma unroll
        for (int r = 0; r < 4; ++r)
          C[(size_t)(row0 + r) * ldc + col] = acc[m][n][r];
      }
    }
  }
}

// ======== fused x-projection: dt GEMM (blocks 0..511) + BC GEMM (512..639) =====
// Shared pool row-partitioned: rows 0..127 = A-tile, rows 128..191 = B-tile.
#define SA_(bq, hl, row) smem[bq][hl][row]
#define SB_(bq, hl, row) smem[bq][hl][128 + (row)]
__global__ __launch_bounds__(256) void xproj_fused(const ushort* __restrict__ Ahi,
                                                   const ushort* __restrict__ Alo,
                                                   const ushort* __restrict__ Wchi,
                                                   const ushort* __restrict__ Wclo,
                                                   const ushort* __restrict__ Wbhi,
                                                   const ushort* __restrict__ Wblo,
                                                   float* __restrict__ DELTA,
                                                   const float* __restrict__ dtb,
                                                   float* __restrict__ BC) {
  __shared__ ushort smem[2][2][192][32];  // 48 KiB
  const int K = 512;
  const int tid = threadIdx.x;
  const int lane = tid & 63;
  const int wid = tid >> 6;
  const int fr = lane & 15;
  const int rcs = (((lane >> 4) ^ ((fr >> 1) & 3)) << 3);
  const int rbase = (lane >> 4) * 4;
  const int wr = wid >> 1, wc = wid & 1;

  if (blockIdx.x < 512) {
    // ---------------- dt GEMM: DELTA = softplus(U @ Wcomb.T + dtb) ------------
    const int bid = blockIdx.x;
    const int q = 512 >> 3;
    const int t = (bid & 7) * q + (bid >> 3);
    const int bx = t % 8;
    const int by = t / 8;
    const int m0 = by * 128;
    const int n0 = bx * 64;

    const int srow = tid >> 2;
    const int koff = (((tid & 3) ^ ((tid >> 3) & 3)) << 3);
    const ushort* Ah_p = Ahi + (size_t)(m0 + srow) * K + koff;
    const ushort* Al_p = Alo + (size_t)(m0 + srow) * K + koff;
    const ushort* Bh_p = Wchi + (size_t)(n0 + srow) * K + koff;
    const ushort* Bl_p = Wclo + (size_t)(n0 + srow) * K + koff;
    const size_t rstep = (size_t)64 * K;
    const int wb = wid * 16;

    f32x4 acc[4][2] = {};

    auto STAGE = [&](int bq, int kk) {
      gload_lds16(Ah_p + kk,         &SA_(bq, 0, wb)[0]);
      gload_lds16(Ah_p + kk + rstep, &SA_(bq, 0, 64 + wb)[0]);
      gload_lds16(Al_p + kk,         &SA_(bq, 1, wb)[0]);
      gload_lds16(Al_p + kk + rstep, &SA_(bq, 1, 64 + wb)[0]);
      gload_lds16(Bh_p + kk,         &SB_(bq, 0, wb)[0]);
      gload_lds16(Bl_p + kk,         &SB_(bq, 1, wb)[0]);
    };

    int cur = 0;
    STAGE(0, 0);
    __syncthreads();

    for (int k0 = 0; k0 < K; k0 += 32) {
      if (k0 + 32 < K) STAGE(cur ^ 1, k0 + 32);
      bf16x8 ah[4], al[4], bh[2], bl[2];
#pragma unroll
      for (int m = 0; m < 4; ++m) {
        const int ar = wr * 64 + m * 16 + fr;
        ah[m] = *(const bf16x8*)&SA_(cur, 0, ar)[rcs];
        al[m] = *(const bf16x8*)&SA_(cur, 1, ar)[rcs];
      }
#pragma unroll
      for (int n = 0; n < 2; ++n) {
        const int br = wc * 32 + n * 16 + fr;
        bh[n] = *(const bf16x8*)&SB_(cur, 0, br)[rcs];
        bl[n] = *(const bf16x8*)&SB_(cur, 1, br)[rcs];
      }
#pragma unroll
      for (int m = 0; m < 4; ++m)
#pragma unroll
        for (int n = 0; n < 2; ++n) {
          acc[m][n] = __builtin_amdgcn_mfma_f32_16x16x32_bf16(ah[m], bh[n],
                                                              acc[m][n], 0, 0, 0);
          acc[m][n] = __builtin_amdgcn_mfma_f32_16x16x32_bf16(ah[m], bl[n],
                                                              acc[m][n], 0, 0, 0);
          acc[m][n] = __builtin_amdgcn_mfma_f32_16x16x32_bf16(al[m], bh[n],
                                                              acc[m][n], 0, 0, 0);
        }
      __syncthreads();
      cur ^= 1;
    }

#pragma unroll
    for (int m = 0; m < 4; ++m) {
      const int row0 = m0 + wr * 64 + m * 16 + rbase;
#pragma unroll
      for (int n = 0; n < 2; ++n) {
        const int col = n0 + wc * 32 + n * 16 + fr;
#pragma unroll
        for (int r = 0; r < 4; ++r) {
          const float x = acc[m][n][r] + dtb[col];
          const float e = __builtin_amdgcn_exp2f(-fabsf(x) * LOG2E);
          DELTA[(size_t)(row0 + r) * 512 + col] =
              fmaxf(x, 0.f) + __log2f(1.f + e) * LN2;
        }
      }
    }
  } else {
    // ---------------- BC GEMM: BC(M,32) = U @ Wbc.T, M-tile 64 ----------------
    const int m0 = (blockIdx.x - 512) * 64;
    const int srow = lane >> 2;
    const int koff = (((lane & 3) ^ ((lane >> 3) & 3)) << 3);
    const ushort* Ah_p = Ahi + (size_t)(m0 + wid * 16 + srow) * K + koff;
    const ushort* Al_p = Alo + (size_t)(m0 + wid * 16 + srow) * K + koff;
    const ushort* B_p = ((wid < 2) ? Wbhi : Wblo) +
                        (size_t)((wid & 1) * 16 + srow) * K + koff;

    f32x4 acc[2] = {};

    auto STAGE = [&](int bq, int kk) {
      gload_lds16(Ah_p + kk, &SA_(bq, 0, wid * 16)[0]);
      gload_lds16(Al_p + kk, &SA_(bq, 1, wid * 16)[0]);
      gload_lds16(B_p + kk, &SB_(bq, wid >> 1, (wid & 1) * 16)[0]);
    };

    int cur = 0;
    STAGE(0, 0);
    __syncthreads();

    for (int k0 = 0; k0 < K; k0 += 32) {
      if (k0 + 32 < K) STAGE(cur ^ 1, k0 + 32);
      bf16x8 ah[2], al[2], bh, bl;
#pragma unroll
      for (int m = 0; m < 2; ++m) {
        const int ar = wr * 32 + m * 16 + fr;
        ah[m] = *(const bf16x8*)&SA_(cur, 0, ar)[rcs];
        al[m] = *(const bf16x8*)&SA_(cur, 1, ar)[rcs];
      }
      const int br = wc * 16 + fr;
      bh = *(const bf16x8*)&SB_(cur, 0, br)[rcs];
      bl = *(const bf16x8*)&SB_(cur, 1, br)[rcs];
#pragma unroll
      for (int m = 0; m < 2; ++m) {
        acc[m] = __builtin_amdgcn_mfma_f32_16x16x32_bf16(ah[m], bh, acc[m], 0, 0, 0);
        acc[m] = __builtin_amdgcn_mfma_f32_16x16x32_bf16(ah[m], bl, acc[m], 0, 0, 0);
        acc[m] = __builtin_amdgcn_mfma_f32_16x16x32_bf16(al[m], bh, acc[m], 0, 0, 0);
      }
      __syncthreads();
      cur ^= 1;
    }

    const int col = wc * 16 + fr;
#pragma unroll
    for (int m = 0; m < 2; ++m) {
      const int row0 = m0 + wr * 32 + m * 16 + rbase;
#pragma unroll
      for (int r = 0; r < 4; ++r)
        BC[(size_t)(row0 + r) * 32 + col] = acc[m][r];
    }
  }
}

// ---------------- prep: split_x + weight prep + c1 + SGATE zero ----------------
__global__ __launch_bounds__(256) void prep_all(const float* __restrict__ x,
                                                const float* __restrict__ gW1,
                                                const float* __restrict__ ipW,
                                                const float* __restrict__ opW,
                                                const float* __restrict__ xW,
                                                const float* __restrict__ dtW,
                                                const float* __restrict__ xstats,
                                                const float* __restrict__ gb1,
                                                ushort* __restrict__ XShi,
                                                ushort* __restrict__ XSlo,
                                                ushort* __restrict__ Whi,
                                                ushort* __restrict__ Wlo,
                                                float* __restrict__ c1,
                                                float* __restrict__ sgate) {
  const int blk = blockIdx.x;
  const int tid = threadIdx.x;
  if (blk < 4096) {
    const int i = (blk * 256 + tid) * 4;
    float4 v = *(const float4*)(x + i);
    ushort h0, l0, h1, l1, h2, l2, h3, l3;
    split2(v.x, h0, l0); split2(v.y, h1, l1);
    split2(v.z, h2, l2); split2(v.w, h3, l3);
    ushort4 hv = {h0, h1, h2, h3}, lv = {l0, l1, l2, l3};
    *(ushort4*)(XShi + i) = hv;
    *(ushort4*)(XSlo + i) = lv;
    return;
  }
  if (blk < 4096 + 1296) {
    const int sub = tid >> 7;
    const int tt = tid & 127;
    const int r = (blk - 4096) * 2 + sub;
    const int j = r - 2048;
    __shared__ float sdt[2][32];
    if (tt < 32 && j >= 0 && j < 512) sdt[sub][tt] = dtW[j * 32 + tt];
    __syncthreads();
    float v[4] = {0.f, 0.f, 0.f, 0.f};
    if (r < 2048) {
      const float* src = (r < 512)    ? gW1 + (size_t)r * 1024
                         : (r < 1536) ? ipW + (size_t)(r - 512) * 512
                                      : opW + (size_t)(r - 1536) * 512;
      const float4 xv = *(const float4*)(src + tt * 4);
      v[0] = xv.x; v[1] = xv.y; v[2] = xv.z; v[3] = xv.w;
    } else if (j < 512) {  // W_comb row
      const int k = tt * 4;
#pragma unroll 8
      for (int rr = 0; rr < 32; ++rr) {
        const float w = sdt[sub][rr];
        const float4 xv = *(const float4*)(xW + rr * 512 + k);
        v[0] = fmaf(w, xv.x, v[0]);
        v[1] = fmaf(w, xv.y, v[1]);
        v[2] = fmaf(w, xv.z, v[2]);
        v[3] = fmaf(w, xv.w, v[3]);
      }
    } else {  // B,C rows
      const float4 xv = *(const float4*)(xW + (size_t)(32 + j - 512) * 512 + tt * 4);
      v[0] = xv.x; v[1] = xv.y; v[2] = xv.z; v[3] = xv.w;
    }
    ushort h[4], l[4];
#pragma unroll
    for (int c = 0; c < 4; ++c) split2(v[c], h[c], l[c]);
    const size_t off = (size_t)r * 512 + tt * 4;
    ushort4 hv = {h[0], h[1], h[2], h[3]}, lv = {l[0], l[1], l[2], l[3]};
    *(ushort4*)(Whi + off) = hv;
    *(ushort4*)(Wlo + off) = lv;
    return;
  }
  if (blk < 4096 + 1296 + 8) {
    // c1
    const int c = blk - (4096 + 1296);
    const int b = c >> 1;
    const int j = ((c & 1) << 8) + tid;
    float acc = gb1[j];
    const float* xs = xstats + b * D_MODEL;
    const float* w = gW1 + (size_t)j * (2 * D_MODEL) + D_MODEL;
    for (int k = 0; k < D_MODEL; k += 4) {
      acc = fmaf(xs[k], w[k], acc);
      acc = fmaf(xs[k + 1], w[k + 1], acc);
      acc = fmaf(xs[k + 2], w[k + 2], acc);
      acc = fmaf(xs[k + 3], w[k + 3], acc);
    }
    c1[b * D_MODEL + j] = acc;
    return;
  }
  // SGATE zero: 8 blocks x 256 threads x 4 floats = 8192
  const int i = ((blk - (4096 + 1296 + 8)) * 256 + tid) * 4;
  float4 z = {0.f, 0.f, 0.f, 0.f};
  *(float4*)(sgate + i) = z;
}

// ---------------- block reduce ------------------------------------------------
__device__ __forceinline__ float block_sum(float v, float* sm) {
#pragma unroll
  for (int m = 32; m; m >>= 1) v += __shfl_xor(v, m);
  const int lane = threadIdx.x & 63, w = threadIdx.x >> 6;
  __syncthreads();
  if (!lane) sm[w] = v;
  __syncthreads();
  return sm[0] + sm[1] + sm[2] + sm[3];
}

// ---------------- gate + layernorm (reads precomputed gate dot) ----------------
__global__ __launch_bounds__(256) void gate_ln_kernel(const float* __restrict__ sdot,
                                                      const float* __restrict__ xsig,
                                                      const float* __restrict__ xstats,
                                                      const float* __restrict__ gb2,
                                                      const float* __restrict__ ln_g,
                                                      const float* __restrict__ ln_b,
                                                      ushort* __restrict__ XNhi,
                                                      ushort* __restrict__ XNlo) {
  __shared__ float red[4];
  const int row = blockIdx.x;
  const int b = row >> 11;
  const int tid = threadIdx.x;
  const size_t rb = (size_t)row * D_MODEL;

  const float gate = 1.f / (1.f + expf(-(sdot[row] + gb2[0])));

  float xr[2];
#pragma unroll
  for (int ii = 0; ii < 2; ++ii) {
    const int j = tid + ii * 256;
    xr[ii] = xsig[rb + j] + gate * xstats[b * D_MODEL + j];
  }
  float sv = xr[0] + xr[1];
  const float mu = block_sum(sv, red) * (1.f / D_MODEL);
  float s2 = (xr[0] - mu) * (xr[0] - mu) + (xr[1] - mu) * (xr[1] - mu);
  const float var = block_sum(s2, red) * (1.f / D_MODEL);
  const float inv = rsqrtf(var + LN_EPS);
#pragma unroll
  for (int ii = 0; ii < 2; ++ii) {
    const int j = tid + ii * 256;
    const float v = (xr[ii] - mu) * inv * ln_g[j] + ln_b[j];
    ushort h, l;
    split2(v, h, l);
    XNhi[rb + j] = h;
    XNlo[rb + j] = l;
  }
}

// ---------------- causal conv(2) + SiLU — row-block, single-pass reads ---------
__global__ __launch_bounds__(256) void conv_silu_kernel(const float* __restrict__ XZ,
                                                        const float* __restrict__ conv_w,
                                                        const float* __restrict__ conv_b,
                                                        ushort* __restrict__ Uhi,
                                                        ushort* __restrict__ Ulo) {
  const int base = blockIdx.x * 16;
  const int j = threadIdx.x * 2;
  const float w0a = conv_w[j * 2 + 0], w1a = conv_w[j * 2 + 1];
  const float w0b = conv_w[j * 2 + 2], w1b = conv_w[j * 2 + 3];
  const float ba = conv_b[j], bb = conv_b[j + 1];
  float2 prev;
  if ((base & (LL - 1)) == 0) {
    prev.x = 0.f; prev.y = 0.f;
  } else {
    prev = *(const float2*)(XZ + (size_t)(base - 1) * (2 * D_INNER) + j);
  }
#pragma unroll 4
  for (int t = 0; t < 16; ++t) {
    const size_t r = base + t;
    const float2 cur = *(const float2*)(XZ + r * (2 * D_INNER) + j);
    float va = ba + w0a * prev.x + w1a * cur.x;
    float vb = bb + w0b * prev.y + w1b * cur.y;
    va = va / (1.f + __builtin_amdgcn_exp2f(-va * LOG2E));
    vb = vb / (1.f + __builtin_amdgcn_exp2f(-vb * LOG2E));
    ushort ha, la, hb, lb;
    split2(va, ha, la);
    split2(vb, hb, lb);
    ushort2 hv = {ha, hb}, lv = {la, lb};
    *(ushort2*)(Uhi + r * D_INNER + j) = hv;
    *(ushort2*)(Ulo + r * D_INNER + j) = lv;
    prev = cur;
  }
}

// ---------------- chunked selective scan (CHUNK=32, r8-proven) -----------------
__global__ __launch_bounds__(256) void scan_part1(const float* __restrict__ DELTA,
                                                  const ushort* __restrict__ Uhi,
                                                  const ushort* __restrict__ Ulo,
                                                  const float* __restrict__ BC,
                                                  const float* __restrict__ A_log,
                                                  float* __restrict__ SLOC,
                                                  float* __restrict__ DSUM) {
  __shared__ __align__(16) float sBC[CHUNK][32];
  const int tid = threadIdx.x;
  const int bid = blockIdx.x;
  const int d = ((bid & 1) << 8) + tid;
  const int c = (bid >> 1) & (NCH - 1);
  const int b = bid >> 7;
  const size_t base = (size_t)b * LL + (size_t)c * CHUNK;

  {
    const int row = tid >> 3, col = (tid & 7) << 2;
    *(float4*)&sBC[row][col] = *(const float4*)(BC + (base + row) * 32 + col);
  }
  float A2[16];
#pragma unroll
  for (int n = 0; n < 16; ++n) A2[n] = -expf(A_log[d * 16 + n]) * LOG2E;
  __syncthreads();

  float S[16];
#pragma unroll
  for (int n = 0; n < 16; ++n) S[n] = 0.f;
  float dsum = 0.f;

#pragma unroll 2
  for (int t = 0; t < CHUNK; ++t) {
    const size_t r = base + t;
    const float delta = DELTA[r * D_INNER + d];
    const float u = bf2f(Uhi[r * D_INNER + d]) + bf2f(Ulo[r * D_INNER + d]);
    dsum += delta;
    const float du = delta * u;
    float Bv[16];
#pragma unroll
    for (int i = 0; i < 4; ++i)
      *(float4*)&Bv[i * 4] = *(const float4*)&sBC[t][i * 4];
#pragma unroll
    for (int n = 0; n < 16; ++n) {
      const float dA = __builtin_amdgcn_exp2f(delta * A2[n]);
      S[n] = fmaf(dA, S[n], du * Bv[n]);
    }
  }
  const size_t ci = ((size_t)b * NCH + c) * D_INNER + d;
#pragma unroll
  for (int i = 0; i < 4; ++i)
    *(float4*)(SLOC + ci * 16 + i * 4) = *(const float4*)&S[i * 4];
  DSUM[ci] = dsum;
}

__global__ __launch_bounds__(256) void scan_combine(const float* __restrict__ SLOC,
                                                    const float* __restrict__ DSUM,
                                                    const float* __restrict__ A_log,
                                                    float* __restrict__ HINIT) {
  const int idx = blockIdx.x * 256 + threadIdx.x;  // 0..32767
  const int b = idx >> 13;
  const int d = (idx >> 4) & (D_INNER - 1);
  const int n = idx & 15;
  const float A2 = -expf(A_log[d * D_STATE + n]) * LOG2E;
  float h = 0.f;
#pragma unroll 4
  for (int c = 0; c < NCH; ++c) {
    const size_t ci = ((size_t)b * NCH + c) * D_INNER + d;
    HINIT[ci * 16 + n] = h;
    const float a = __builtin_amdgcn_exp2f(A2 * DSUM[ci]);
    h = fmaf(a, h, SLOC[ci * 16 + n]);
  }
}

__global__ __launch_bounds__(256) void scan_part3(const float* __restrict__ DELTA,
                                                  const ushort* __restrict__ Uhi,
                                                  const ushort* __restrict__ Ulo,
                                                  const float* __restrict__ BC,
                                                  const float* __restrict__ XZ,
                                                  const float* __restrict__ A_log,
                                                  const float* __restrict__ Dp,
                                                  const float* __restrict__ HINIT,
                                                  ushort* __restrict__ Yhi,
                                                  ushort* __restrict__ Ylo) {
  __shared__ __align__(16) float sBC[CHUNK][32];
  const int tid = threadIdx.x;
  const int bid = blockIdx.x;
  const int d = ((bid & 1) << 8) + tid;
  const int c = (bid >> 1) & (NCH - 1);
  const int b = bid >> 7;
  const size_t base = (size_t)b * LL + (size_t)c * CHUNK;

  {
    const int row = tid >> 3, col = (tid & 7) << 2;
    *(float4*)&sBC[row][col] = *(const float4*)(BC + (base + row) * 32 + col);
  }
  float A2[16];
#pragma unroll
  for (int n = 0; n < 16; ++n) A2[n] = -expf(A_log[d * 16 + n]) * LOG2E;
  const float Dpd = Dp[d];

  const size_t ci = ((size_t)b * NCH + c) * D_INNER + d;
  float h[16];
#pragma unroll
  for (int i = 0; i < 4; ++i)
    *(float4*)&h[i * 4] = *(const float4*)(HINIT + ci * 16 + i * 4);
  __syncthreads();

#pragma unroll 2
  for (int t = 0; t < CHUNK; ++t) {
    const size_t r = base + t;
    const float delta = DELTA[r * D_INNER + d];
    const float u = bf2f(Uhi[r * D_INNER + d]) + bf2f(Ulo[r * D_INNER + d]);
    const float z = XZ[r * (2 * D_INNER) + D_INNER + d];
    const float du = delta * u;
    float BCv[32];
#pragma unroll
    for (int i = 0; i < 8; ++i)
      *(float4*)&BCv[i * 4] = *(const float4*)&sBC[t][i * 4];
    float y = 0.f;
#pragma unroll
    for (int n = 0; n < 16; ++n) {
      const float dA = __builtin_amdgcn_exp2f(delta * A2[n]);
      h[n] = fmaf(dA, h[n], du * BCv[n]);
      y = fmaf(h[n], BCv[16 + n], y);
    }
    const float sz = z / (1.f + __builtin_amdgcn_exp2f(-z * LOG2E));
    const float o = (y + Dpd * u) * sz;
    ushort hh, ll;
    split2(o, hh, ll);
    Yhi[r * D_INNER + d] = hh;
    Ylo[r * D_INNER + d] = ll;
  }
}

// =============================================================================
extern "C" void kernel_launch(void* const* d_in, const int* in_sizes, int n_in,
                              void* d_out, int out_size, void* d_ws, size_t ws_size,
                              hipStream_t stream) {
  const float* x_signal = (const float*)d_in[0];
  const float* x_stats  = (const float*)d_in[1];
  const float* gW1      = (const float*)d_in[2];
  const float* gb1      = (const float*)d_in[3];
  const float* gW2      = (const float*)d_in[4];
  const float* gb2      = (const float*)d_in[5];
  const float* ln_g     = (const float*)d_in[6];
  const float* ln_b     = (const float*)d_in[7];
  const float* in_proj_W = (const float*)d_in[8];
  const float* conv_w   = (const float*)d_in[9];
  const float* conv_b   = (const float*)d_in[10];
  const float* x_proj_W = (const float*)d_in[11];
  const float* dt_proj_W = (const float*)d_in[12];
  const float* dt_proj_b = (const float*)d_in[13];
  const float* A_log    = (const float*)d_in[14];
  const float* Dp       = (const float*)d_in[15];
  const float* out_proj_W = (const float*)d_in[16];
  float* out = (float*)d_out;

  float* ws = (float*)d_ws;
  const size_t NE = (size_t)MROWS * D_MODEL;  // 4,194,304
  float* H    = ws;                     // Yhi/Ylo region
  float* XNf  = H + NE;                 // XN hi/lo bf16; later DELTA f32
  float* XZ   = XNf + NE;               // 8192x1024 f32; first XShi/XSlo
  float* UHL  = XZ + 2 * NE;            // Uhi/Ulo bf16
  float* BC   = UHL + NE;               // 8192x32 f32
  float* C1   = BC + (size_t)MROWS * 32;
  float* SGATE = C1 + BB * D_MODEL;     // 8192 f32 gate dots
  float* SLOC = SGATE + MROWS;
  float* DSUM = SLOC + (size_t)BB * NCH * D_INNER * D_STATE;
  float* HINIT = DSUM + (size_t)BB * NCH * D_INNER;
  float* WSP  = HINIT + (size_t)BB * NCH * D_INNER * D_STATE;

  ushort* XNhi = (ushort*)XNf;
  ushort* XNlo = XNhi + NE;
  ushort* XShi = (ushort*)XZ;
  ushort* XSlo = XShi + NE;
  ushort* Yhi  = (ushort*)H;
  ushort* Ylo  = Yhi + NE;
  ushort* Uhi  = (ushort*)UHL;
  ushort* Ulo  = Uhi + NE;
  ushort* Whi  = (ushort*)WSP;          // 2592 rows x 512
  ushort* Wlo  = Whi + (size_t)2592 * 512;
  float* DELTA = XNf;

  // 0) split x / prep weights / c1 / SGATE-zero in one dispatch
  prep_all<<<dim3(4096 + 1296 + 8 + 8), dim3(256), 0, stream>>>(
      x_signal, gW1, in_proj_W, out_proj_W, x_proj_W, dt_proj_W, x_stats, gb1,
      XShi, XSlo, Whi, Wlo, C1, SGATE);

  // 1) gate dots: SGATE[row] = sum relu(x@W1a + c1)*gW2  (grid 8x64 = 512)
  gemm_mfma<1><<<dim3(8 * 64), dim3(256), 0, stream>>>(
      XShi, XSlo, Whi, Wlo, nullptr, 0, D_MODEL, 8, C1, gW2, SGATE);

  // 2) gate + layernorm -> XNhi/XNlo
  gate_ln_kernel<<<dim3(MROWS), dim3(256), 0, stream>>>(SGATE, x_signal, x_stats,
                                                        gb2, ln_g, ln_b, XNhi, XNlo);

  // 3) XZ = XN @ in_proj_W.T   (grid 16x64 = 1024)
  gemm_mfma<0><<<dim3(16 * 64), dim3(256), 0, stream>>>(
      XNhi, XNlo, Whi + (size_t)512 * 512, Wlo + (size_t)512 * 512, XZ, 2 * D_INNER,
      D_MODEL, 16, nullptr, nullptr, nullptr);

  // 4) conv + silu -> Uhi/Ulo  (grid 512, 16 rows/block)
  conv_silu_kernel<<<dim3(MROWS / 16), dim3(256), 0, stream>>>(XZ, conv_w, conv_b,
                                                               Uhi, Ulo);

  // 5) fused x-projection: DELTA (blocks 0..511) + BC (blocks 512..639)
  xproj_fused<<<dim3(640), dim3(256), 0, stream>>>(
      Uhi, Ulo, Whi + (size_t)2048 * 512, Wlo + (size_t)2048 * 512,
      Whi + (size_t)2560 * 512, Wlo + (size_t)2560 * 512, DELTA, dt_proj_b, BC);

  // 6) chunked selective scan (CHUNK=32) -> Yhi/Ylo
  scan_part1<<<dim3(BB * NCH * 2), dim3(256), 0, stream>>>(DELTA, Uhi, Ulo, BC, A_log,
                                                           SLOC, DSUM);
  scan_combine<<<dim3(128), dim3(256), 0, stream>>>(SLOC, DSUM, A_log, HINIT);
  scan_part3<<<dim3(BB * NCH * 2), dim3(256), 0, stream>>>(DELTA, Uhi, Ulo, BC, XZ,
                                                           A_log, Dp, HINIT, Yhi, Ylo);

  // 7) out = Y @ out_proj_W.T   (grid 8x64 = 512)
  gemm_mfma<0><<<dim3(8 * 64), dim3(256), 0, stream>>>(
      Yhi, Ylo, Whi + (size_t)1536 * 512, Wlo + (size_t)1536 * 512, out, D_MODEL,
      D_INNER, 8, nullptr, nullptr, nullptr);
}